// Round 7
// baseline (1991.757 us; speedup 1.0000x reference)
//
#include <hip/hip_runtime.h>
#include <math.h>

#define NPTS 8192
#define DIM 32
#define MAX_ITER 10
#define TOL 1e-4f
#define DAMP 0.5f
#define LOG2E 1.4426950408889634f

// ---- scratch layout inside OUT_A (floats from A base); all consumed before k_apass2 ----
#define OFF_MSP   0u           // 64*33*8192 mean-shift partials
#define OFF_CCUR  17301504u    // 8192*32
#define OFF_CNEW  17563648u    // 8192*32
#define OFF_NX    17825792u    // 8192
#define OFF_NC    17833984u    // 8192
#define OFF_PV    17842176u    // 32*8192 argmin partial val
#define OFF_PJ    18366464u    // 32*8192 argmin partial idx (int)
#define OFF_RKP   18890752u    // 32*8192 rank partials (int)
#define OFF_MSH   19152896u    // 16 maxshift slots (uint)
#define OFF_SCO   19152912u    // 8192 scores (int)
#define OFF_ORD   19161104u    // 8192 order (int)
// d_ws: ps softmax-sum partials (32*8192 floats = 1 MB; survives apass2's A writes)

// ---------------- init: c0 = x, nx = nc = ||x||^2; zero scores & maxshift ----------------
__global__ __launch_bounds__(256) void k_init(const float* __restrict__ x,
                                              float* __restrict__ c0,
                                              float* __restrict__ nx,
                                              float* __restrict__ nc,
                                              int* __restrict__ scores,
                                              unsigned int* __restrict__ msh) {
    int p = blockIdx.x * blockDim.x + threadIdx.x;
    const float4* xr = (const float4*)(x + (size_t)p * DIM);
    float4* cr = (float4*)(c0 + (size_t)p * DIM);
    float s = 0.f;
#pragma unroll
    for (int q = 0; q < 8; ++q) {
        float4 v = xr[q];
        cr[q] = v;
        s += v.x * v.x + v.y * v.y + v.z * v.z + v.w * v.w;
    }
    nx[p] = s;
    nc[p] = s;
    scores[p] = 0;
    if (blockIdx.x == 0 && threadIdx.x < 16) msh[threadIdx.x] = 0u;
}

// ---------------- mean-shift partial pass: LDS-staged 128-j slice, 2 i-rows/lane ----------
// grid 1024 = 16 i-tiles(512 rows) x 64 j-splits(128 j). block 256 = 4 waves.
// waves_per_eu(2,4): allow ~150-170 arch VGPRs so xi/acc arrays stay out of AGPRs.
__global__ __launch_bounds__(256)
__attribute__((amdgpu_waves_per_eu(2, 4)))
void k_ms2(const float* __restrict__ x,
           const float* __restrict__ nx,
           const float* __restrict__ c,
           const float* __restrict__ nc,
           const float* __restrict__ sigma_p,
           float* __restrict__ P) {
    __shared__ float sc[128 * 32];    // 16 KB: c rows
    __shared__ float sxx[128 * 32];   // 16 KB: x rows
    __shared__ float snc[128];

    int t = threadIdx.x;
    int wv = __builtin_amdgcn_readfirstlane(t >> 6);
    int lane = t & 63;
    int it = (int)blockIdx.x >> 6, js = (int)blockIdx.x & 63;
    int i0 = it * 512 + wv * 128 + lane;
    int i1 = i0 + 64;
    int jb = js * 128;

    float sg = sigma_p[0];
    float ng2 = -LOG2E / (2.f * sg * sg);   // w = exp2(ng2 * sq)

    float xi0[DIM], xi1[DIM];
    {
        const float4* xr0 = (const float4*)(x + (size_t)i0 * DIM);
        const float4* xr1 = (const float4*)(x + (size_t)i1 * DIM);
#pragma unroll
        for (int q = 0; q < 8; ++q) {
            float4 a = xr0[q], b = xr1[q];
            xi0[4 * q] = a.x; xi0[4 * q + 1] = a.y; xi0[4 * q + 2] = a.z; xi0[4 * q + 3] = a.w;
            xi1[4 * q] = b.x; xi1[4 * q + 1] = b.y; xi1[4 * q + 2] = b.z; xi1[4 * q + 3] = b.w;
        }
    }
    float nx0 = nx[i0], nx1 = nx[i1];

    {   // stage C + X (1024 float4 each, coalesced) + nc
        const float4* srcc = (const float4*)(c + (size_t)jb * DIM);
        const float4* srcx = (const float4*)(x + (size_t)jb * DIM);
        float4* dstc = (float4*)sc;
        float4* dstx = (float4*)sxx;
        for (int k = t; k < 1024; k += 256) { dstc[k] = srcc[k]; dstx[k] = srcx[k]; }
        if (t < 128) snc[t] = nc[jb + t];
    }
    __syncthreads();

    float acc0[DIM], acc1[DIM];
#pragma unroll
    for (int d = 0; d < DIM; ++d) { acc0[d] = 0.f; acc1[d] = 0.f; }
    float ws0 = 0.f, ws1 = 0.f;

    for (int jj = 0; jj < 128; ++jj) {
        int rb = jj * 32;
        float w0, w1;
        {
            float a0 = 0.f, a1 = 0.f, a2 = 0.f, a3 = 0.f;
            float b0 = 0.f, b1 = 0.f, b2 = 0.f, b3 = 0.f;
#pragma unroll
            for (int q = 0; q < 8; ++q) {
                float4 cv = *(const float4*)(sc + rb + 4 * q);
                a0 = fmaf(xi0[4 * q + 0], cv.x, a0);
                a1 = fmaf(xi0[4 * q + 1], cv.y, a1);
                a2 = fmaf(xi0[4 * q + 2], cv.z, a2);
                a3 = fmaf(xi0[4 * q + 3], cv.w, a3);
                b0 = fmaf(xi1[4 * q + 0], cv.x, b0);
                b1 = fmaf(xi1[4 * q + 1], cv.y, b1);
                b2 = fmaf(xi1[4 * q + 2], cv.z, b2);
                b3 = fmaf(xi1[4 * q + 3], cv.w, b3);
            }
            float ncj = snc[jj];
            float sq0 = fmaxf(fmaf(-2.f, (a0 + a1) + (a2 + a3), nx0 + ncj), 0.f);
            float sq1 = fmaxf(fmaf(-2.f, (b0 + b1) + (b2 + b3), nx1 + ncj), 0.f);
            w0 = __builtin_amdgcn_exp2f(ng2 * sq0);
            w1 = __builtin_amdgcn_exp2f(ng2 * sq1);
        }
        ws0 += w0; ws1 += w1;
#pragma unroll
        for (int q = 0; q < 8; ++q) {
            float4 xv = *(const float4*)(sxx + rb + 4 * q);
            acc0[4 * q + 0] = fmaf(w0, xv.x, acc0[4 * q + 0]);
            acc0[4 * q + 1] = fmaf(w0, xv.y, acc0[4 * q + 1]);
            acc0[4 * q + 2] = fmaf(w0, xv.z, acc0[4 * q + 2]);
            acc0[4 * q + 3] = fmaf(w0, xv.w, acc0[4 * q + 3]);
            acc1[4 * q + 0] = fmaf(w1, xv.x, acc1[4 * q + 0]);
            acc1[4 * q + 1] = fmaf(w1, xv.y, acc1[4 * q + 1]);
            acc1[4 * q + 2] = fmaf(w1, xv.z, acc1[4 * q + 2]);
            acc1[4 * q + 3] = fmaf(w1, xv.w, acc1[4 * q + 3]);
        }
    }

    size_t base = ((size_t)js * 33) * NPTS + i0;
#pragma unroll
    for (int d = 0; d < DIM; ++d) {
        P[base + (size_t)d * NPTS] = acc0[d];
        P[base + (size_t)d * NPTS + 64] = acc1[d];
    }
    P[base + (size_t)32 * NPTS] = ws0;
    P[base + (size_t)32 * NPTS + 64] = ws1;
}

// ---------------- reduce partials (64 splits) -> c_new, maxshift ----------------
// grid 128: block = 64 points x 4 js-quarters; LDS combine.
__global__ __launch_bounds__(256) void k_reduce(const float* __restrict__ P,
                                                const float* __restrict__ c_cur,
                                                float* __restrict__ c_new,
                                                unsigned int* __restrict__ maxshift) {
    __shared__ float red[256][33];
    int t = threadIdx.x;
    int pl = t & 63, qs = t >> 6;
    int i = blockIdx.x * 64 + pl;
    float tot[33];
#pragma unroll
    for (int d = 0; d < 33; ++d) tot[d] = 0.f;
    for (int js = qs * 16; js < qs * 16 + 16; ++js) {
        size_t base = ((size_t)js * 33) * NPTS + i;
#pragma unroll
        for (int d = 0; d < 33; ++d) tot[d] += P[base + (size_t)d * NPTS];
    }
#pragma unroll
    for (int d = 0; d < 33; ++d) red[t][d] = tot[d];
    __syncthreads();
    if (t < 64) {
        int ii = blockIdx.x * 64 + t;
        float tt[33];
#pragma unroll
        for (int d = 0; d < 33; ++d)
            tt[d] = (red[t][d] + red[t + 64][d]) + (red[t + 128][d] + red[t + 192][d]);
        float ws = tt[32];
        float inv = __builtin_amdgcn_rcpf(ws);
        inv = inv * (2.f - ws * inv);  // one NR step
        const float* co = c_cur + (size_t)ii * DIM;
        float sh2 = 0.f;
        float ncv[DIM];
#pragma unroll
        for (int d = 0; d < DIM; ++d) {
            float v = tt[d] * inv;
            ncv[d] = v;
            float df = v - co[d];
            sh2 = fmaf(df, df, sh2);
        }
        float4* dst = (float4*)(c_new + (size_t)ii * DIM);
#pragma unroll
        for (int q = 0; q < 8; ++q)
            dst[q] = make_float4(ncv[4 * q], ncv[4 * q + 1], ncv[4 * q + 2], ncv[4 * q + 3]);
        atomicMax(maxshift, __float_as_uint(__builtin_amdgcn_sqrtf(sh2)));
    }
}

// ---------------- damped update + nc refresh (skipped when converged) ----------------
__global__ __launch_bounds__(256) void k_update(float* __restrict__ c_cur,
                                                const float* __restrict__ c_new,
                                                float* __restrict__ nc,
                                                const unsigned int* __restrict__ maxshift) {
    if (__uint_as_float(*maxshift) < TOL) return;
    int i = blockIdx.x * 256 + threadIdx.x;
    float4* cc = (float4*)(c_cur + (size_t)i * DIM);
    const float4* cn = (const float4*)(c_new + (size_t)i * DIM);
    float s = 0.f;
#pragma unroll
    for (int q = 0; q < 8; ++q) {
        float4 a = cc[q], b = cn[q];
        float4 r = make_float4(DAMP * a.x + (1.f - DAMP) * b.x,
                               DAMP * a.y + (1.f - DAMP) * b.y,
                               DAMP * a.z + (1.f - DAMP) * b.z,
                               DAMP * a.w + (1.f - DAMP) * b.w);
        cc[q] = r;
        s += r.x * r.x + r.y * r.y + r.z * r.z + r.w * r.w;
    }
    nc[i] = s;
}

// ---------------- scores: LDS-staged j-slice, 2-row partial argmin (32 splits) ----------
__global__ __launch_bounds__(256, 2) void k_scores2(const float* __restrict__ x,
                                                    const float* __restrict__ nx,
                                                    const float* __restrict__ c,
                                                    const float* __restrict__ nc,
                                                    float* __restrict__ pv,
                                                    int* __restrict__ pj) {
    __shared__ float sc[256 * 32];
    __shared__ float snc[256];
    int t = threadIdx.x;
    int wv = __builtin_amdgcn_readfirstlane(t >> 6);
    int lane = t & 63;
    int it = (int)blockIdx.x >> 5, js = (int)blockIdx.x & 31;
    int p0 = it * 512 + wv * 128 + lane;
    int p1 = p0 + 64;
    int jb = js * 256;

    float xi0[DIM], xi1[DIM];
    {
        const float4* xr0 = (const float4*)(x + (size_t)p0 * DIM);
        const float4* xr1 = (const float4*)(x + (size_t)p1 * DIM);
#pragma unroll
        for (int q = 0; q < 8; ++q) {
            float4 a = xr0[q], b = xr1[q];
            xi0[4 * q] = a.x; xi0[4 * q + 1] = a.y; xi0[4 * q + 2] = a.z; xi0[4 * q + 3] = a.w;
            xi1[4 * q] = b.x; xi1[4 * q + 1] = b.y; xi1[4 * q + 2] = b.z; xi1[4 * q + 3] = b.w;
        }
    }
    float nxp0 = nx[p0], nxp1 = nx[p1];

    {
        const float4* srcc = (const float4*)(c + (size_t)jb * DIM);
        float4* dstc = (float4*)sc;
        for (int k = t; k < 2048; k += 256) dstc[k] = srcc[k];
        snc[t] = nc[jb + t];
    }
    __syncthreads();

    float bv0 = INFINITY, bv1 = INFINITY;
    int bj0 = jb, bj1 = jb;
    for (int jj = 0; jj < 256; ++jj) {
        int rb = jj * 32;
        float a0 = 0.f, a1 = 0.f, a2 = 0.f, a3 = 0.f;
        float b0 = 0.f, b1 = 0.f, b2 = 0.f, b3 = 0.f;
#pragma unroll
        for (int q = 0; q < 8; ++q) {
            float4 cv = *(const float4*)(sc + rb + 4 * q);
            a0 = fmaf(xi0[4 * q + 0], cv.x, a0);
            a1 = fmaf(xi0[4 * q + 1], cv.y, a1);
            a2 = fmaf(xi0[4 * q + 2], cv.z, a2);
            a3 = fmaf(xi0[4 * q + 3], cv.w, a3);
            b0 = fmaf(xi1[4 * q + 0], cv.x, b0);
            b1 = fmaf(xi1[4 * q + 1], cv.y, b1);
            b2 = fmaf(xi1[4 * q + 2], cv.z, b2);
            b3 = fmaf(xi1[4 * q + 3], cv.w, b3);
        }
        float ncj = snc[jj];
        float sq0 = fmaxf(fmaf(-2.f, (a0 + a1) + (a2 + a3), nxp0 + ncj), 0.f);
        float sq1 = fmaxf(fmaf(-2.f, (b0 + b1) + (b2 + b3), nxp1 + ncj), 0.f);
        if (sq0 < bv0) { bv0 = sq0; bj0 = jb + jj; }   // strict <: first min wins
        if (sq1 < bv1) { bv1 = sq1; bj1 = jb + jj; }
    }
    pv[(size_t)js * NPTS + p0] = bv0;
    pj[(size_t)js * NPTS + p0] = bj0;
    pv[(size_t)js * NPTS + p1] = bv1;
    pj[(size_t)js * NPTS + p1] = bj1;
}

__global__ __launch_bounds__(256) void k_score_comb(const float* __restrict__ pv,
                                                    const int* __restrict__ pj,
                                                    int* __restrict__ scores) {
    int p = blockIdx.x * 256 + threadIdx.x;
    float bv = pv[p];
    int bj = pj[p];
    for (int js = 1; js < 32; ++js) {
        float v = pv[(size_t)js * NPTS + p];
        int j = pj[(size_t)js * NPTS + p];
        if (v < bv) { bv = v; bj = j; }  // ascending js: first global min
    }
    atomicAdd(&scores[bj], 1);
}

// ---------------- stable descending rank (split + combine) ----------------
__global__ __launch_bounds__(256) void k_rank_part(const int* __restrict__ scores,
                                                   int* __restrict__ rkp) {
    int t = threadIdx.x;
    int wv = __builtin_amdgcn_readfirstlane(t >> 6);
    int lane = t & 63;
    int it = (int)blockIdx.x >> 5, js = (int)blockIdx.x & 31;
    int p = it * 256 + wv * 64 + lane;
    int sp = scores[p];
    int j0 = js * 256;
    int r = 0;
    for (int jj = 0; jj < 256; ++jj) {
        int sj = scores[j0 + jj];
        int j = j0 + jj;
        r += (sj > sp) || (sj == sp && j < p);
    }
    rkp[(size_t)js * NPTS + p] = r;
}

__global__ __launch_bounds__(256) void k_rank_comb(const int* __restrict__ rkp,
                                                   int* __restrict__ order) {
    int p = blockIdx.x * 256 + threadIdx.x;
    int r = 0;
    for (int js = 0; js < 32; ++js) r += rkp[(size_t)js * NPTS + p];
    order[r] = p;
}

// ---------------- greedy NMS scan (single block, ballot fast-forward) ----------------
__global__ __launch_bounds__(1024) void k_nms(const float* __restrict__ c,
                                              const int* __restrict__ order,
                                              const int* __restrict__ scores,
                                              const float* __restrict__ sigma_p,
                                              float* __restrict__ keep_out) {
    __shared__ int s_ord[NPTS];
    __shared__ unsigned char kp[NPTS];
    __shared__ int s_first[16];
    __shared__ int s_next;
    int t = threadIdx.x;
    for (int q = t; q < NPTS; q += 1024) { s_ord[q] = order[q]; kp[q] = 1; }
    __syncthreads();
    float sg = sigma_p[0];
    float thr2 = sg * sg;

    int k = 0;
    while (k < NPTS) {
        int cand = k + t;
        bool hit = (cand < NPTS) && (kp[s_ord[cand]] != 0);
        unsigned long long b = __ballot(hit);
        int wave = t >> 6;
        if ((t & 63) == 0)
            s_first[wave] = b ? (k + (wave << 6) + (__ffsll((unsigned long long)b) - 1))
                              : 0x7fffffff;
        __syncthreads();
        if (t == 0) {
            int mn = s_first[0];
            for (int w2 = 1; w2 < 16; ++w2) mn = min(mn, s_first[w2]);
            s_next = mn;
        }
        __syncthreads();
        int kf = s_next;
        if (kf == 0x7fffffff) { k += 1024; continue; }

        int idx = s_ord[kf];
        float ci[DIM];
        const float4* cr = (const float4*)(c + (size_t)idx * DIM);
#pragma unroll
        for (int q = 0; q < 8; ++q) {
            float4 v = cr[q];
            ci[4 * q] = v.x; ci[4 * q + 1] = v.y; ci[4 * q + 2] = v.z; ci[4 * q + 3] = v.w;
        }
#pragma unroll
        for (int m2 = 0; m2 < 8; ++m2) {
            int j = t + m2 * 1024;
            const float4* cj = (const float4*)(c + (size_t)j * DIM);
            float sq = 0.f;
#pragma unroll
            for (int q = 0; q < 8; ++q) {
                float4 v = cj[q];
                float e0 = v.x - ci[4 * q], e1 = v.y - ci[4 * q + 1];
                float e2 = v.z - ci[4 * q + 2], e3 = v.w - ci[4 * q + 3];
                sq += e0 * e0 + e1 * e1 + e2 * e2 + e3 * e3;
            }
            if (j != idx && sq < thr2) kp[j] = 0;
        }
        __syncthreads();
        if (t == 0) kp[idx] = (scores[idx] > 0) ? 1 : 0;
        __syncthreads();
        k = kf + 1;
    }
    __syncthreads();
    for (int q = t; q < NPTS; q += 1024) keep_out[q] = kp[q] ? 1.0f : 0.0f;
}

// ---------------- assignment pass 1: LDS-staged, 2-row partial sum (M == 0) ----------------
__global__ __launch_bounds__(256, 2) void k_apass1(const float* __restrict__ x,
                                                   const float* __restrict__ nx,
                                                   const float* __restrict__ c,
                                                   const float* __restrict__ nc,
                                                   const float* __restrict__ keepf,
                                                   float* __restrict__ ps) {
    __shared__ float sc[256 * 32];
    __shared__ float snc[256];
    __shared__ float skp[256];
    int t = threadIdx.x;
    int wv = __builtin_amdgcn_readfirstlane(t >> 6);
    int lane = t & 63;
    int it = (int)blockIdx.x >> 5, js = (int)blockIdx.x & 31;
    int p0 = it * 512 + wv * 128 + lane;
    int p1 = p0 + 64;
    int jb = js * 256;

    float xi0[DIM], xi1[DIM];
    {
        const float4* xr0 = (const float4*)(x + (size_t)p0 * DIM);
        const float4* xr1 = (const float4*)(x + (size_t)p1 * DIM);
#pragma unroll
        for (int q = 0; q < 8; ++q) {
            float4 a = xr0[q], b = xr1[q];
            xi0[4 * q] = a.x; xi0[4 * q + 1] = a.y; xi0[4 * q + 2] = a.z; xi0[4 * q + 3] = a.w;
            xi1[4 * q] = b.x; xi1[4 * q + 1] = b.y; xi1[4 * q + 2] = b.z; xi1[4 * q + 3] = b.w;
        }
    }
    float nxp0 = nx[p0], nxp1 = nx[p1];

    {
        const float4* srcc = (const float4*)(c + (size_t)jb * DIM);
        float4* dstc = (float4*)sc;
        for (int k = t; k < 2048; k += 256) dstc[k] = srcc[k];
        snc[t] = nc[jb + t];
        skp[t] = (keepf[jb + t] > 0.5f) ? 0.f : -1e38f;
    }
    __syncthreads();

    float S0 = 0.f, S1 = 0.f;
    for (int jj = 0; jj < 256; ++jj) {
        int rb = jj * 32;
        float a0 = 0.f, a1 = 0.f, a2 = 0.f, a3 = 0.f;
        float b0 = 0.f, b1 = 0.f, b2 = 0.f, b3 = 0.f;
#pragma unroll
        for (int q = 0; q < 8; ++q) {
            float4 cv = *(const float4*)(sc + rb + 4 * q);
            a0 = fmaf(xi0[4 * q + 0], cv.x, a0);
            a1 = fmaf(xi0[4 * q + 1], cv.y, a1);
            a2 = fmaf(xi0[4 * q + 2], cv.z, a2);
            a3 = fmaf(xi0[4 * q + 3], cv.w, a3);
            b0 = fmaf(xi1[4 * q + 0], cv.x, b0);
            b1 = fmaf(xi1[4 * q + 1], cv.y, b1);
            b2 = fmaf(xi1[4 * q + 2], cv.z, b2);
            b3 = fmaf(xi1[4 * q + 3], cv.w, b3);
        }
        float ncj = snc[jj];
        float kadd = skp[jj];
        float sq0 = fmaxf(fmaf(-2.f, (a0 + a1) + (a2 + a3), nxp0 + ncj), 0.f);
        float sq1 = fmaxf(fmaf(-2.f, (b0 + b1) + (b2 + b3), nxp1 + ncj), 0.f);
        float r0 = __builtin_amdgcn_sqrtf(sq0 + 1e-12f);
        float r1 = __builtin_amdgcn_sqrtf(sq1 + 1e-12f);
        S0 += __builtin_amdgcn_exp2f(fmaf(r0, -LOG2E, kadd));
        S1 += __builtin_amdgcn_exp2f(fmaf(r1, -LOG2E, kadd));
    }
    ps[(size_t)js * NPTS + p0] = S0;
    ps[(size_t)js * NPTS + p1] = S1;
}

// ---------------- assignment pass 2: 2 j's per lane, x-tile broadcast from LDS ------------
// grid 1024 = 64 p-tiles(128) x 16 j-tiles(512). block 256 = 4 waves x 64 lanes x 2 j.
__global__ __launch_bounds__(256)
__attribute__((amdgpu_waves_per_eu(3, 4)))
void k_apass2(const float* __restrict__ x,
              const float* __restrict__ c,
              const float* __restrict__ keepf,
              const float* __restrict__ ps,
              float* __restrict__ A) {
    __shared__ float sx[128 * 36];   // row stride 36 floats (16B aligned)
    __shared__ float snx[128];
    __shared__ float sscale[128];
    __shared__ float spart[256];
    int t = threadIdx.x;
    int wv = __builtin_amdgcn_readfirstlane(t >> 6);
    int lane = t & 63;
    int pt = (int)blockIdx.x >> 4, jt = (int)blockIdx.x & 15;
    int p0 = pt * 128, j0 = jt * 512;

    {   // stage x-tile
        const float4* src = (const float4*)(x + (size_t)p0 * DIM) + t * 4;
        int row = t >> 1, colh = (t & 1) * 16;
        float4* dst = (float4*)(sx + row * 36 + colh);
        float s = 0.f;
#pragma unroll
        for (int q = 0; q < 4; ++q) {
            float4 v = src[q];
            dst[q] = v;
            s += v.x * v.x + v.y * v.y + v.z * v.z + v.w * v.w;
        }
        spart[t] = s;
    }
    __syncthreads();
    if (t < 128) {
        snx[t] = spart[2 * t] + spart[2 * t + 1];
        float SS = 0.f;
        for (int js = 0; js < 32; ++js) SS += ps[(size_t)js * NPTS + p0 + t];
        sscale[t] = 1.f / SS;
    }

    int ja = j0 + wv * 64 + lane;
    int jbx = ja + 256;
    float cj0[DIM], cj1[DIM];
    float nc0 = 0.f, nc1 = 0.f;
    {
        const float4* cra = (const float4*)(c + (size_t)ja * DIM);
        const float4* crb = (const float4*)(c + (size_t)jbx * DIM);
#pragma unroll
        for (int q = 0; q < 8; ++q) {
            float4 va = cra[q], vb = crb[q];
            cj0[4 * q] = va.x; cj0[4 * q + 1] = va.y; cj0[4 * q + 2] = va.z; cj0[4 * q + 3] = va.w;
            cj1[4 * q] = vb.x; cj1[4 * q + 1] = vb.y; cj1[4 * q + 2] = vb.z; cj1[4 * q + 3] = vb.w;
            nc0 += va.x * va.x + va.y * va.y + va.z * va.z + va.w * va.w;
            nc1 += vb.x * vb.x + vb.y * vb.y + vb.z * vb.z + vb.w * vb.w;
        }
    }
    float kadd0 = (keepf[ja] > 0.5f) ? 0.f : -1e38f;
    float kadd1 = (keepf[jbx] > 0.5f) ? 0.f : -1e38f;
    __syncthreads();

    for (int pp = 0; pp < 128; ++pp) {
        int rb = pp * 36;
        float d0 = 0.f, d1 = 0.f, d2 = 0.f, d3 = 0.f;
        float e0 = 0.f, e1 = 0.f, e2 = 0.f, e3 = 0.f;
#pragma unroll
        for (int q = 0; q < 8; ++q) {
            float4 v = *(const float4*)(sx + rb + 4 * q);
            d0 = fmaf(cj0[4 * q + 0], v.x, d0);
            d1 = fmaf(cj0[4 * q + 1], v.y, d1);
            d2 = fmaf(cj0[4 * q + 2], v.z, d2);
            d3 = fmaf(cj0[4 * q + 3], v.w, d3);
            e0 = fmaf(cj1[4 * q + 0], v.x, e0);
            e1 = fmaf(cj1[4 * q + 1], v.y, e1);
            e2 = fmaf(cj1[4 * q + 2], v.z, e2);
            e3 = fmaf(cj1[4 * q + 3], v.w, e3);
        }
        float nxp = snx[pp], scl = sscale[pp];
        float sqa = fmaxf(fmaf(-2.f, (d0 + d1) + (d2 + d3), nxp + nc0), 0.f);
        float sqb = fmaxf(fmaf(-2.f, (e0 + e1) + (e2 + e3), nxp + nc1), 0.f);
        float ra = __builtin_amdgcn_sqrtf(sqa + 1e-12f);
        float rbq = __builtin_amdgcn_sqrtf(sqb + 1e-12f);
        float ta = fmaf(ra, -LOG2E, kadd0);
        float tb = fmaf(rbq, -LOG2E, kadd1);
        float* rowp = A + (size_t)(p0 + pp) * NPTS;
        rowp[ja] = __builtin_amdgcn_exp2f(ta) * scl;
        rowp[jbx] = __builtin_amdgcn_exp2f(tb) * scl;
    }
}

extern "C" void kernel_launch(void* const* d_in, const int* in_sizes, int n_in,
                              void* d_out, int out_size, void* d_ws, size_t ws_size,
                              hipStream_t stream) {
    const float* x = (const float*)d_in[0];
    const float* sigma = (const float*)d_in[1];

    float* out = (float*)d_out;
    float* OUT_C = out;                          // NPTS*DIM
    float* A = out + (size_t)NPTS * DIM;         // NPTS*NPTS
    float* OUT_K = A + (size_t)NPTS * NPTS;      // NPTS

    float* msP = A + OFF_MSP;
    float* c_cur = A + OFF_CCUR;
    float* c_new = A + OFF_CNEW;
    float* nx = A + OFF_NX;
    float* nc = A + OFF_NC;
    float* pv = A + OFF_PV;
    int* pj = (int*)(A + OFF_PJ);
    int* rkp = (int*)(A + OFF_RKP);
    unsigned int* msh = (unsigned int*)(A + OFF_MSH);
    int* scores = (int*)(A + OFF_SCO);
    int* order = (int*)(A + OFF_ORD);
    float* ps = (float*)d_ws;                    // 1 MB, survives apass2

    k_init<<<NPTS / 256, 256, 0, stream>>>(x, c_cur, nx, nc, scores, msh);
    for (int itr = 0; itr < MAX_ITER; ++itr) {
        k_ms2<<<1024, 256, 0, stream>>>(x, nx, c_cur, nc, sigma, msP);
        k_reduce<<<NPTS / 64, 256, 0, stream>>>(msP, c_cur, c_new, msh + itr);
        k_update<<<NPTS / 256, 256, 0, stream>>>(c_cur, c_new, nc, msh + itr);
    }
    hipMemcpyAsync(OUT_C, c_cur, (size_t)NPTS * DIM * sizeof(float),
                   hipMemcpyDeviceToDevice, stream);

    k_scores2<<<512, 256, 0, stream>>>(x, nx, OUT_C, nc, pv, pj);
    k_score_comb<<<NPTS / 256, 256, 0, stream>>>(pv, pj, scores);
    k_rank_part<<<1024, 256, 0, stream>>>(scores, rkp);
    k_rank_comb<<<NPTS / 256, 256, 0, stream>>>(rkp, order);
    k_nms<<<1, 1024, 0, stream>>>(OUT_C, order, scores, sigma, OUT_K);

    k_apass1<<<512, 256, 0, stream>>>(x, nx, OUT_C, nc, OUT_K, ps);
    k_apass2<<<1024, 256, 0, stream>>>(x, OUT_C, OUT_K, ps, A);
}

// Round 8
// 1882.812 us; speedup vs baseline: 1.0579x; 1.0579x over previous
//
#include <hip/hip_runtime.h>
#include <math.h>

#define NPTS 8192
#define DIM 32
#define MAX_ITER 10
#define TOL 1e-4f
#define DAMP 0.5f
#define LOG2E 1.4426950408889634f

#define AS4 __attribute__((address_space(4)))
typedef float f32x16 __attribute__((ext_vector_type(16)));

// constant-address-space cast (CK pattern): uniform loads become s_load_* (SGPR dest)
__device__ __forceinline__ const AS4 float* cptr(const float* p) {
    return (const AS4 float*)(unsigned long long)p;
}
__device__ __forceinline__ const AS4 int* cptri(const int* p) {
    return (const AS4 int*)(unsigned long long)p;
}

// ---- scratch layout inside OUT_A (floats from A base); all consumed before k_apass2 ----
#define OFF_MSP   0u          // 32*33*8192 mean-shift partials
#define OFF_CCUR  8650752u    // 8192*32 (x4B: 64B-aligned)
#define OFF_CNEW  8912896u    // 8192*32
#define OFF_NX    9175040u    // 8192
#define OFF_NC    9183232u    // 8192
#define OFF_PV    9191424u    // 32*8192 argmin partial val
#define OFF_PJ    9453568u    // 32*8192 argmin partial idx (int)
#define OFF_RKP   9715712u    // 32*8192 rank partials (int)
#define OFF_MSH   9977856u    // 16 maxshift slots (uint)
#define OFF_SCO   9977872u    // 8192 scores (int)
#define OFF_ORD   9986064u    // 8192 order (int)
// d_ws: ps softmax-sum partials (32*8192 floats = 1 MB; survives apass2's A writes)

// ---------------- init: c0 = x, nx = nc = ||x||^2; zero scores & maxshift ----------------
__global__ __launch_bounds__(256) void k_init(const float* __restrict__ x,
                                              float* __restrict__ c0,
                                              float* __restrict__ nx,
                                              float* __restrict__ nc,
                                              int* __restrict__ scores,
                                              unsigned int* __restrict__ msh) {
    int p = blockIdx.x * blockDim.x + threadIdx.x;
    const float4* xr = (const float4*)(x + (size_t)p * DIM);
    float4* cr = (float4*)(c0 + (size_t)p * DIM);
    float s = 0.f;
#pragma unroll
    for (int q = 0; q < 8; ++q) {
        float4 v = xr[q];
        cr[q] = v;
        s += v.x * v.x + v.y * v.y + v.z * v.z + v.w * v.w;
    }
    nx[p] = s;
    nc[p] = s;
    scores[p] = 0;
    if (blockIdx.x == 0 && threadIdx.x < 16) msh[threadIdx.x] = 0u;
}

// ---------------- mean-shift partial pass: SMEM-streamed uniform j, 2 i-rows/lane --------
// grid 512 = 16 i-tiles(512 rows) x 32 j-splits(256 j). block 256 = 4 waves. No LDS.
// C/X rows + nc stream through the scalar pipe (addrspace(4) -> s_load_dwordx16),
// freeing VALU+LDS entirely; FMAs consume SGPR operands directly.
__global__ __launch_bounds__(256) void k_ms2(const float* __restrict__ x,
                                             const float* __restrict__ nx,
                                             const float* __restrict__ c,
                                             const float* __restrict__ nc,
                                             const float* __restrict__ sigma_p,
                                             float* __restrict__ P) {
    int t = threadIdx.x;
    int wv = __builtin_amdgcn_readfirstlane(t >> 6);
    int lane = t & 63;
    int it = (int)blockIdx.x >> 5, js = (int)blockIdx.x & 31;
    int i0 = it * 512 + wv * 128 + lane;
    int i1 = i0 + 64;
    int jb = js * 256;

    float sg = sigma_p[0];
    float ng2 = -LOG2E / (2.f * sg * sg);   // w = exp2(ng2 * sq)

    float xi0[DIM], xi1[DIM];
    {
        const float4* xr0 = (const float4*)(x + (size_t)i0 * DIM);
        const float4* xr1 = (const float4*)(x + (size_t)i1 * DIM);
#pragma unroll
        for (int q = 0; q < 8; ++q) {
            float4 a = xr0[q], b = xr1[q];
            xi0[4 * q] = a.x; xi0[4 * q + 1] = a.y; xi0[4 * q + 2] = a.z; xi0[4 * q + 3] = a.w;
            xi1[4 * q] = b.x; xi1[4 * q + 1] = b.y; xi1[4 * q + 2] = b.z; xi1[4 * q + 3] = b.w;
        }
    }
    float nx0 = nx[i0], nx1 = nx[i1];

    float acc0[DIM], acc1[DIM];
#pragma unroll
    for (int d = 0; d < DIM; ++d) { acc0[d] = 0.f; acc1[d] = 0.f; }
    float ws0 = 0.f, ws1 = 0.f;

    const AS4 f32x16* c16 = (const AS4 f32x16*)cptr(c + (size_t)jb * DIM);
    const AS4 f32x16* x16 = (const AS4 f32x16*)cptr(x + (size_t)jb * DIM);
    const AS4 float* nc4 = cptr(nc + jb);

    for (int jj = 0; jj < 256; ++jj) {
        f32x16 C0 = c16[2 * jj], C1 = c16[2 * jj + 1];
        float ncj = nc4[jj];
        float w0, w1;
        {
            float a0 = 0.f, a1 = 0.f, a2 = 0.f, a3 = 0.f;
            float b0 = 0.f, b1 = 0.f, b2 = 0.f, b3 = 0.f;
#pragma unroll
            for (int q = 0; q < 4; ++q) {
                a0 = fmaf(xi0[4 * q + 0], C0[4 * q + 0], a0);
                a1 = fmaf(xi0[4 * q + 1], C0[4 * q + 1], a1);
                a2 = fmaf(xi0[4 * q + 2], C0[4 * q + 2], a2);
                a3 = fmaf(xi0[4 * q + 3], C0[4 * q + 3], a3);
                b0 = fmaf(xi1[4 * q + 0], C0[4 * q + 0], b0);
                b1 = fmaf(xi1[4 * q + 1], C0[4 * q + 1], b1);
                b2 = fmaf(xi1[4 * q + 2], C0[4 * q + 2], b2);
                b3 = fmaf(xi1[4 * q + 3], C0[4 * q + 3], b3);
            }
#pragma unroll
            for (int q = 0; q < 4; ++q) {
                a0 = fmaf(xi0[16 + 4 * q + 0], C1[4 * q + 0], a0);
                a1 = fmaf(xi0[16 + 4 * q + 1], C1[4 * q + 1], a1);
                a2 = fmaf(xi0[16 + 4 * q + 2], C1[4 * q + 2], a2);
                a3 = fmaf(xi0[16 + 4 * q + 3], C1[4 * q + 3], a3);
                b0 = fmaf(xi1[16 + 4 * q + 0], C1[4 * q + 0], b0);
                b1 = fmaf(xi1[16 + 4 * q + 1], C1[4 * q + 1], b1);
                b2 = fmaf(xi1[16 + 4 * q + 2], C1[4 * q + 2], b2);
                b3 = fmaf(xi1[16 + 4 * q + 3], C1[4 * q + 3], b3);
            }
            float sq0 = fmaxf(fmaf(-2.f, (a0 + a1) + (a2 + a3), nx0 + ncj), 0.f);
            float sq1 = fmaxf(fmaf(-2.f, (b0 + b1) + (b2 + b3), nx1 + ncj), 0.f);
            w0 = __builtin_amdgcn_exp2f(ng2 * sq0);
            w1 = __builtin_amdgcn_exp2f(ng2 * sq1);
        }
        ws0 += w0; ws1 += w1;
        f32x16 X0 = x16[2 * jj], X1 = x16[2 * jj + 1];
#pragma unroll
        for (int e = 0; e < 16; ++e) {
            acc0[e] = fmaf(w0, X0[e], acc0[e]);
            acc1[e] = fmaf(w1, X0[e], acc1[e]);
        }
#pragma unroll
        for (int e = 0; e < 16; ++e) {
            acc0[16 + e] = fmaf(w0, X1[e], acc0[16 + e]);
            acc1[16 + e] = fmaf(w1, X1[e], acc1[16 + e]);
        }
    }

    size_t base = ((size_t)js * 33) * NPTS + i0;
#pragma unroll
    for (int d = 0; d < DIM; ++d) {
        P[base + (size_t)d * NPTS] = acc0[d];
        P[base + (size_t)d * NPTS + 64] = acc1[d];
    }
    P[base + (size_t)32 * NPTS] = ws0;
    P[base + (size_t)32 * NPTS + 64] = ws1;
}

// ---------------- reduce partials -> c_new, maxshift ----------------
__global__ __launch_bounds__(256) void k_reduce(const float* __restrict__ P,
                                                const float* __restrict__ c_cur,
                                                float* __restrict__ c_new,
                                                unsigned int* __restrict__ maxshift) {
    int i = blockIdx.x * 256 + threadIdx.x;
    float tot[33];
#pragma unroll
    for (int d = 0; d < 33; ++d) tot[d] = 0.f;
    for (int js = 0; js < 32; ++js) {
        size_t base = ((size_t)js * 33) * NPTS + i;
#pragma unroll
        for (int d = 0; d < 33; ++d) tot[d] += P[base + (size_t)d * NPTS];
    }
    float ws = tot[32];
    float inv = __builtin_amdgcn_rcpf(ws);
    inv = inv * (2.f - ws * inv);  // one NR step
    const float* co = c_cur + (size_t)i * DIM;
    float sh2 = 0.f;
    float ncv[DIM];
#pragma unroll
    for (int d = 0; d < DIM; ++d) {
        float v = tot[d] * inv;
        ncv[d] = v;
        float df = v - co[d];
        sh2 = fmaf(df, df, sh2);
    }
    float4* dst = (float4*)(c_new + (size_t)i * DIM);
#pragma unroll
    for (int q = 0; q < 8; ++q)
        dst[q] = make_float4(ncv[4 * q], ncv[4 * q + 1], ncv[4 * q + 2], ncv[4 * q + 3]);
    atomicMax(maxshift, __float_as_uint(__builtin_amdgcn_sqrtf(sh2)));
}

// ---------------- damped update + nc refresh (skipped when converged) ----------------
__global__ __launch_bounds__(256) void k_update(float* __restrict__ c_cur,
                                                const float* __restrict__ c_new,
                                                float* __restrict__ nc,
                                                const unsigned int* __restrict__ maxshift) {
    if (__uint_as_float(*maxshift) < TOL) return;
    int i = blockIdx.x * 256 + threadIdx.x;
    float4* cc = (float4*)(c_cur + (size_t)i * DIM);
    const float4* cn = (const float4*)(c_new + (size_t)i * DIM);
    float s = 0.f;
#pragma unroll
    for (int q = 0; q < 8; ++q) {
        float4 a = cc[q], b = cn[q];
        float4 r = make_float4(DAMP * a.x + (1.f - DAMP) * b.x,
                               DAMP * a.y + (1.f - DAMP) * b.y,
                               DAMP * a.z + (1.f - DAMP) * b.z,
                               DAMP * a.w + (1.f - DAMP) * b.w);
        cc[q] = r;
        s += r.x * r.x + r.y * r.y + r.z * r.z + r.w * r.w;
    }
    nc[i] = s;
}

// ---------------- scores: SMEM-streamed, 2-row partial argmin ----------------
__global__ __launch_bounds__(256) void k_scores2(const float* __restrict__ x,
                                                 const float* __restrict__ nx,
                                                 const float* __restrict__ c,
                                                 const float* __restrict__ nc,
                                                 float* __restrict__ pv,
                                                 int* __restrict__ pj) {
    int t = threadIdx.x;
    int wv = __builtin_amdgcn_readfirstlane(t >> 6);
    int lane = t & 63;
    int it = (int)blockIdx.x >> 5, js = (int)blockIdx.x & 31;
    int p0 = it * 512 + wv * 128 + lane;
    int p1 = p0 + 64;
    int jb = js * 256;

    float xi0[DIM], xi1[DIM];
    {
        const float4* xr0 = (const float4*)(x + (size_t)p0 * DIM);
        const float4* xr1 = (const float4*)(x + (size_t)p1 * DIM);
#pragma unroll
        for (int q = 0; q < 8; ++q) {
            float4 a = xr0[q], b = xr1[q];
            xi0[4 * q] = a.x; xi0[4 * q + 1] = a.y; xi0[4 * q + 2] = a.z; xi0[4 * q + 3] = a.w;
            xi1[4 * q] = b.x; xi1[4 * q + 1] = b.y; xi1[4 * q + 2] = b.z; xi1[4 * q + 3] = b.w;
        }
    }
    float nxp0 = nx[p0], nxp1 = nx[p1];

    const AS4 f32x16* c16 = (const AS4 f32x16*)cptr(c + (size_t)jb * DIM);
    const AS4 float* nc4 = cptr(nc + jb);

    float bv0 = INFINITY, bv1 = INFINITY;
    int bj0 = jb, bj1 = jb;
    for (int jj = 0; jj < 256; ++jj) {
        f32x16 C0 = c16[2 * jj], C1 = c16[2 * jj + 1];
        float ncj = nc4[jj];
        float a0 = 0.f, a1 = 0.f, a2 = 0.f, a3 = 0.f;
        float b0 = 0.f, b1 = 0.f, b2 = 0.f, b3 = 0.f;
#pragma unroll
        for (int q = 0; q < 4; ++q) {
            a0 = fmaf(xi0[4 * q + 0], C0[4 * q + 0], a0);
            a1 = fmaf(xi0[4 * q + 1], C0[4 * q + 1], a1);
            a2 = fmaf(xi0[4 * q + 2], C0[4 * q + 2], a2);
            a3 = fmaf(xi0[4 * q + 3], C0[4 * q + 3], a3);
            b0 = fmaf(xi1[4 * q + 0], C0[4 * q + 0], b0);
            b1 = fmaf(xi1[4 * q + 1], C0[4 * q + 1], b1);
            b2 = fmaf(xi1[4 * q + 2], C0[4 * q + 2], b2);
            b3 = fmaf(xi1[4 * q + 3], C0[4 * q + 3], b3);
        }
#pragma unroll
        for (int q = 0; q < 4; ++q) {
            a0 = fmaf(xi0[16 + 4 * q + 0], C1[4 * q + 0], a0);
            a1 = fmaf(xi0[16 + 4 * q + 1], C1[4 * q + 1], a1);
            a2 = fmaf(xi0[16 + 4 * q + 2], C1[4 * q + 2], a2);
            a3 = fmaf(xi0[16 + 4 * q + 3], C1[4 * q + 3], a3);
            b0 = fmaf(xi1[16 + 4 * q + 0], C1[4 * q + 0], b0);
            b1 = fmaf(xi1[16 + 4 * q + 1], C1[4 * q + 1], b1);
            b2 = fmaf(xi1[16 + 4 * q + 2], C1[4 * q + 2], b2);
            b3 = fmaf(xi1[16 + 4 * q + 3], C1[4 * q + 3], b3);
        }
        float sq0 = fmaxf(fmaf(-2.f, (a0 + a1) + (a2 + a3), nxp0 + ncj), 0.f);
        float sq1 = fmaxf(fmaf(-2.f, (b0 + b1) + (b2 + b3), nxp1 + ncj), 0.f);
        if (sq0 < bv0) { bv0 = sq0; bj0 = jb + jj; }   // strict <: first min wins
        if (sq1 < bv1) { bv1 = sq1; bj1 = jb + jj; }
    }
    pv[(size_t)js * NPTS + p0] = bv0;
    pj[(size_t)js * NPTS + p0] = bj0;
    pv[(size_t)js * NPTS + p1] = bv1;
    pj[(size_t)js * NPTS + p1] = bj1;
}

__global__ __launch_bounds__(256) void k_score_comb(const float* __restrict__ pv,
                                                    const int* __restrict__ pj,
                                                    int* __restrict__ scores) {
    int p = blockIdx.x * 256 + threadIdx.x;
    float bv = pv[p];
    int bj = pj[p];
    for (int js = 1; js < 32; ++js) {
        float v = pv[(size_t)js * NPTS + p];
        int j = pj[(size_t)js * NPTS + p];
        if (v < bv) { bv = v; bj = j; }  // ascending js: first global min
    }
    atomicAdd(&scores[bj], 1);
}

// ---------------- stable descending rank (split + combine) ----------------
__global__ __launch_bounds__(256) void k_rank_part(const int* __restrict__ scores,
                                                   int* __restrict__ rkp) {
    int t = threadIdx.x;
    int wv = __builtin_amdgcn_readfirstlane(t >> 6);
    int lane = t & 63;
    int it = (int)blockIdx.x >> 5, js = (int)blockIdx.x & 31;
    int p = it * 256 + wv * 64 + lane;
    int sp = scores[p];
    int j0 = js * 256;
    const AS4 int* sc4 = cptri(scores);
    int r = 0;
    for (int jj = 0; jj < 256; ++jj) {
        int sj = sc4[j0 + jj];
        int j = j0 + jj;
        r += (sj > sp) || (sj == sp && j < p);
    }
    rkp[(size_t)js * NPTS + p] = r;
}

__global__ __launch_bounds__(256) void k_rank_comb(const int* __restrict__ rkp,
                                                   int* __restrict__ order) {
    int p = blockIdx.x * 256 + threadIdx.x;
    int r = 0;
    for (int js = 0; js < 32; ++js) r += rkp[(size_t)js * NPTS + p];
    order[r] = p;
}

// ---------------- greedy NMS scan (single block, ballot fast-forward) ----------------
__global__ __launch_bounds__(1024) void k_nms(const float* __restrict__ c,
                                              const int* __restrict__ order,
                                              const int* __restrict__ scores,
                                              const float* __restrict__ sigma_p,
                                              float* __restrict__ keep_out) {
    __shared__ int s_ord[NPTS];
    __shared__ unsigned char kp[NPTS];
    __shared__ int s_first[16];
    __shared__ int s_next;
    int t = threadIdx.x;
    for (int q = t; q < NPTS; q += 1024) { s_ord[q] = order[q]; kp[q] = 1; }
    __syncthreads();
    float sg = sigma_p[0];
    float thr2 = sg * sg;

    int k = 0;
    while (k < NPTS) {
        int cand = k + t;
        bool hit = (cand < NPTS) && (kp[s_ord[cand]] != 0);
        unsigned long long b = __ballot(hit);
        int wave = t >> 6;
        if ((t & 63) == 0)
            s_first[wave] = b ? (k + (wave << 6) + (__ffsll((unsigned long long)b) - 1))
                              : 0x7fffffff;
        __syncthreads();
        if (t == 0) {
            int mn = s_first[0];
            for (int w2 = 1; w2 < 16; ++w2) mn = min(mn, s_first[w2]);
            s_next = mn;
        }
        __syncthreads();
        int kf = s_next;
        if (kf == 0x7fffffff) { k += 1024; continue; }

        int idx = s_ord[kf];
        float ci[DIM];
        const float4* cr = (const float4*)(c + (size_t)idx * DIM);
#pragma unroll
        for (int q = 0; q < 8; ++q) {
            float4 v = cr[q];
            ci[4 * q] = v.x; ci[4 * q + 1] = v.y; ci[4 * q + 2] = v.z; ci[4 * q + 3] = v.w;
        }
#pragma unroll
        for (int m2 = 0; m2 < 8; ++m2) {
            int j = t + m2 * 1024;
            const float4* cj = (const float4*)(c + (size_t)j * DIM);
            float sq = 0.f;
#pragma unroll
            for (int q = 0; q < 8; ++q) {
                float4 v = cj[q];
                float e0 = v.x - ci[4 * q], e1 = v.y - ci[4 * q + 1];
                float e2 = v.z - ci[4 * q + 2], e3 = v.w - ci[4 * q + 3];
                sq += e0 * e0 + e1 * e1 + e2 * e2 + e3 * e3;
            }
            if (j != idx && sq < thr2) kp[j] = 0;
        }
        __syncthreads();
        if (t == 0) kp[idx] = (scores[idx] > 0) ? 1 : 0;
        __syncthreads();
        k = kf + 1;
    }
    __syncthreads();
    for (int q = t; q < NPTS; q += 1024) keep_out[q] = kp[q] ? 1.0f : 0.0f;
}

// ---------------- assignment pass 1: SMEM-streamed, 2-row partial sum (M == 0) -----------
__global__ __launch_bounds__(256) void k_apass1(const float* __restrict__ x,
                                                const float* __restrict__ nx,
                                                const float* __restrict__ c,
                                                const float* __restrict__ nc,
                                                const float* __restrict__ keepf,
                                                float* __restrict__ ps) {
    int t = threadIdx.x;
    int wv = __builtin_amdgcn_readfirstlane(t >> 6);
    int lane = t & 63;
    int it = (int)blockIdx.x >> 5, js = (int)blockIdx.x & 31;
    int p0 = it * 512 + wv * 128 + lane;
    int p1 = p0 + 64;
    int jb = js * 256;

    float xi0[DIM], xi1[DIM];
    {
        const float4* xr0 = (const float4*)(x + (size_t)p0 * DIM);
        const float4* xr1 = (const float4*)(x + (size_t)p1 * DIM);
#pragma unroll
        for (int q = 0; q < 8; ++q) {
            float4 a = xr0[q], b = xr1[q];
            xi0[4 * q] = a.x; xi0[4 * q + 1] = a.y; xi0[4 * q + 2] = a.z; xi0[4 * q + 3] = a.w;
            xi1[4 * q] = b.x; xi1[4 * q + 1] = b.y; xi1[4 * q + 2] = b.z; xi1[4 * q + 3] = b.w;
        }
    }
    float nxp0 = nx[p0], nxp1 = nx[p1];

    const AS4 f32x16* c16 = (const AS4 f32x16*)cptr(c + (size_t)jb * DIM);
    const AS4 float* nc4 = cptr(nc + jb);
    const AS4 float* kp4 = cptr(keepf + jb);

    float S0 = 0.f, S1 = 0.f;
    for (int jj = 0; jj < 256; ++jj) {
        f32x16 C0 = c16[2 * jj], C1 = c16[2 * jj + 1];
        float ncj = nc4[jj];
        float kadd = (kp4[jj] > 0.5f) ? 0.f : -1e38f;
        float a0 = 0.f, a1 = 0.f, a2 = 0.f, a3 = 0.f;
        float b0 = 0.f, b1 = 0.f, b2 = 0.f, b3 = 0.f;
#pragma unroll
        for (int q = 0; q < 4; ++q) {
            a0 = fmaf(xi0[4 * q + 0], C0[4 * q + 0], a0);
            a1 = fmaf(xi0[4 * q + 1], C0[4 * q + 1], a1);
            a2 = fmaf(xi0[4 * q + 2], C0[4 * q + 2], a2);
            a3 = fmaf(xi0[4 * q + 3], C0[4 * q + 3], a3);
            b0 = fmaf(xi1[4 * q + 0], C0[4 * q + 0], b0);
            b1 = fmaf(xi1[4 * q + 1], C0[4 * q + 1], b1);
            b2 = fmaf(xi1[4 * q + 2], C0[4 * q + 2], b2);
            b3 = fmaf(xi1[4 * q + 3], C0[4 * q + 3], b3);
        }
#pragma unroll
        for (int q = 0; q < 4; ++q) {
            a0 = fmaf(xi0[16 + 4 * q + 0], C1[4 * q + 0], a0);
            a1 = fmaf(xi0[16 + 4 * q + 1], C1[4 * q + 1], a1);
            a2 = fmaf(xi0[16 + 4 * q + 2], C1[4 * q + 2], a2);
            a3 = fmaf(xi0[16 + 4 * q + 3], C1[4 * q + 3], a3);
            b0 = fmaf(xi1[16 + 4 * q + 0], C1[4 * q + 0], b0);
            b1 = fmaf(xi1[16 + 4 * q + 1], C1[4 * q + 1], b1);
            b2 = fmaf(xi1[16 + 4 * q + 2], C1[4 * q + 2], b2);
            b3 = fmaf(xi1[16 + 4 * q + 3], C1[4 * q + 3], b3);
        }
        float sq0 = fmaxf(fmaf(-2.f, (a0 + a1) + (a2 + a3), nxp0 + ncj), 0.f);
        float sq1 = fmaxf(fmaf(-2.f, (b0 + b1) + (b2 + b3), nxp1 + ncj), 0.f);
        float r0 = __builtin_amdgcn_sqrtf(sq0 + 1e-12f);
        float r1 = __builtin_amdgcn_sqrtf(sq1 + 1e-12f);
        S0 += __builtin_amdgcn_exp2f(fmaf(r0, -LOG2E, kadd));
        S1 += __builtin_amdgcn_exp2f(fmaf(r1, -LOG2E, kadd));
    }
    ps[(size_t)js * NPTS + p0] = S0;
    ps[(size_t)js * NPTS + p1] = S1;
}

// ---------------- assignment pass 2: 2 j's per lane, x-row via SMEM ----------------
// grid 1024 = 64 p-tiles(128) x 16 j-tiles(512). block 256 = 4 waves x 64 lanes x 2 j.
__global__ __launch_bounds__(256) void k_apass2(const float* __restrict__ x,
                                                const float* __restrict__ c,
                                                const float* __restrict__ keepf,
                                                const float* __restrict__ ps,
                                                float* __restrict__ A) {
    __shared__ float snx[128];
    __shared__ float sscale[128];
    int t = threadIdx.x;
    int wv = __builtin_amdgcn_readfirstlane(t >> 6);
    int lane = t & 63;
    int pt = (int)blockIdx.x >> 4, jt = (int)blockIdx.x & 15;
    int p0 = pt * 128, j0 = jt * 512;

    if (t < 128) {   // per-row norm + softmax scale
        const float4* xr = (const float4*)(x + (size_t)(p0 + t) * DIM);
        float s = 0.f;
#pragma unroll
        for (int q = 0; q < 8; ++q) {
            float4 v = xr[q];
            s += v.x * v.x + v.y * v.y + v.z * v.z + v.w * v.w;
        }
        snx[t] = s;
        float SS = 0.f;
        for (int js = 0; js < 32; ++js) SS += ps[(size_t)js * NPTS + p0 + t];
        sscale[t] = 1.f / SS;
    }

    int ja = j0 + wv * 64 + lane;
    int jbx = ja + 256;
    float cj0[DIM], cj1[DIM];
    float nc0 = 0.f, nc1 = 0.f;
    {
        const float4* cra = (const float4*)(c + (size_t)ja * DIM);
        const float4* crb = (const float4*)(c + (size_t)jbx * DIM);
#pragma unroll
        for (int q = 0; q < 8; ++q) {
            float4 va = cra[q], vb = crb[q];
            cj0[4 * q] = va.x; cj0[4 * q + 1] = va.y; cj0[4 * q + 2] = va.z; cj0[4 * q + 3] = va.w;
            cj1[4 * q] = vb.x; cj1[4 * q + 1] = vb.y; cj1[4 * q + 2] = vb.z; cj1[4 * q + 3] = vb.w;
            nc0 += va.x * va.x + va.y * va.y + va.z * va.z + va.w * va.w;
            nc1 += vb.x * vb.x + vb.y * vb.y + vb.z * vb.z + vb.w * vb.w;
        }
    }
    float kadd0 = (keepf[ja] > 0.5f) ? 0.f : -1e38f;
    float kadd1 = (keepf[jbx] > 0.5f) ? 0.f : -1e38f;
    __syncthreads();

    const AS4 f32x16* x16 = (const AS4 f32x16*)cptr(x + (size_t)p0 * DIM);

    for (int pp = 0; pp < 128; ++pp) {
        f32x16 X0 = x16[2 * pp], X1 = x16[2 * pp + 1];
        float d0 = 0.f, d1 = 0.f, d2 = 0.f, d3 = 0.f;
        float e0 = 0.f, e1 = 0.f, e2 = 0.f, e3 = 0.f;
#pragma unroll
        for (int q = 0; q < 4; ++q) {
            d0 = fmaf(cj0[4 * q + 0], X0[4 * q + 0], d0);
            d1 = fmaf(cj0[4 * q + 1], X0[4 * q + 1], d1);
            d2 = fmaf(cj0[4 * q + 2], X0[4 * q + 2], d2);
            d3 = fmaf(cj0[4 * q + 3], X0[4 * q + 3], d3);
            e0 = fmaf(cj1[4 * q + 0], X0[4 * q + 0], e0);
            e1 = fmaf(cj1[4 * q + 1], X0[4 * q + 1], e1);
            e2 = fmaf(cj1[4 * q + 2], X0[4 * q + 2], e2);
            e3 = fmaf(cj1[4 * q + 3], X0[4 * q + 3], e3);
        }
#pragma unroll
        for (int q = 0; q < 4; ++q) {
            d0 = fmaf(cj0[16 + 4 * q + 0], X1[4 * q + 0], d0);
            d1 = fmaf(cj0[16 + 4 * q + 1], X1[4 * q + 1], d1);
            d2 = fmaf(cj0[16 + 4 * q + 2], X1[4 * q + 2], d2);
            d3 = fmaf(cj0[16 + 4 * q + 3], X1[4 * q + 3], d3);
            e0 = fmaf(cj1[16 + 4 * q + 0], X1[4 * q + 0], e0);
            e1 = fmaf(cj1[16 + 4 * q + 1], X1[4 * q + 1], e1);
            e2 = fmaf(cj1[16 + 4 * q + 2], X1[4 * q + 2], e2);
            e3 = fmaf(cj1[16 + 4 * q + 3], X1[4 * q + 3], e3);
        }
        float nxp = snx[pp], scl = sscale[pp];
        float sqa = fmaxf(fmaf(-2.f, (d0 + d1) + (d2 + d3), nxp + nc0), 0.f);
        float sqb = fmaxf(fmaf(-2.f, (e0 + e1) + (e2 + e3), nxp + nc1), 0.f);
        float ra = __builtin_amdgcn_sqrtf(sqa + 1e-12f);
        float rb = __builtin_amdgcn_sqrtf(sqb + 1e-12f);
        float ta = fmaf(ra, -LOG2E, kadd0);
        float tb = fmaf(rb, -LOG2E, kadd1);
        float* rowp = A + (size_t)(p0 + pp) * NPTS;
        rowp[ja] = __builtin_amdgcn_exp2f(ta) * scl;
        rowp[jbx] = __builtin_amdgcn_exp2f(tb) * scl;
    }
}

extern "C" void kernel_launch(void* const* d_in, const int* in_sizes, int n_in,
                              void* d_out, int out_size, void* d_ws, size_t ws_size,
                              hipStream_t stream) {
    const float* x = (const float*)d_in[0];
    const float* sigma = (const float*)d_in[1];

    float* out = (float*)d_out;
    float* OUT_C = out;                          // NPTS*DIM
    float* A = out + (size_t)NPTS * DIM;         // NPTS*NPTS
    float* OUT_K = A + (size_t)NPTS * NPTS;      // NPTS

    float* msP = A + OFF_MSP;
    float* c_cur = A + OFF_CCUR;
    float* c_new = A + OFF_CNEW;
    float* nx = A + OFF_NX;
    float* nc = A + OFF_NC;
    float* pv = A + OFF_PV;
    int* pj = (int*)(A + OFF_PJ);
    int* rkp = (int*)(A + OFF_RKP);
    unsigned int* msh = (unsigned int*)(A + OFF_MSH);
    int* scores = (int*)(A + OFF_SCO);
    int* order = (int*)(A + OFF_ORD);
    float* ps = (float*)d_ws;                    // 1 MB, survives apass2

    k_init<<<NPTS / 256, 256, 0, stream>>>(x, c_cur, nx, nc, scores, msh);
    for (int itr = 0; itr < MAX_ITER; ++itr) {
        k_ms2<<<512, 256, 0, stream>>>(x, nx, c_cur, nc, sigma, msP);
        k_reduce<<<NPTS / 256, 256, 0, stream>>>(msP, c_cur, c_new, msh + itr);
        k_update<<<NPTS / 256, 256, 0, stream>>>(c_cur, c_new, nc, msh + itr);
    }
    hipMemcpyAsync(OUT_C, c_cur, (size_t)NPTS * DIM * sizeof(float),
                   hipMemcpyDeviceToDevice, stream);

    k_scores2<<<512, 256, 0, stream>>>(x, nx, OUT_C, nc, pv, pj);
    k_score_comb<<<NPTS / 256, 256, 0, stream>>>(pv, pj, scores);
    k_rank_part<<<1024, 256, 0, stream>>>(scores, rkp);
    k_rank_comb<<<NPTS / 256, 256, 0, stream>>>(rkp, order);
    k_nms<<<1, 1024, 0, stream>>>(OUT_C, order, scores, sigma, OUT_K);

    k_apass1<<<512, 256, 0, stream>>>(x, nx, OUT_C, nc, OUT_K, ps);
    k_apass2<<<1024, 256, 0, stream>>>(x, OUT_C, OUT_K, ps, A);
}